// Round 5
// baseline (101.724 us; speedup 1.0000x reference)
//
#include <hip/hip_runtime.h>
#include <hip/hip_bf16.h>

typedef __attribute__((ext_vector_type(8))) short bf16x8;
typedef __attribute__((ext_vector_type(16))) float f32x16;
typedef __attribute__((ext_vector_type(4))) unsigned short u16x4;

#define TT 128
#define DD 256
#define BK 64

__device__ __forceinline__ unsigned short f2bf(float f) {
  unsigned int x = __float_as_uint(f);
  x += 0x7fffu + ((x >> 16) & 1u);          // round-to-nearest-even
  return (unsigned short)(x >> 16);
}

__device__ __forceinline__ bf16x8 pack8(float4 lo, float4 hi) {
  bf16x8 v;
  v[0] = (short)f2bf(lo.x); v[1] = (short)f2bf(lo.y);
  v[2] = (short)f2bf(lo.z); v[3] = (short)f2bf(lo.w);
  v[4] = (short)f2bf(hi.x); v[5] = (short)f2bf(hi.y);
  v[6] = (short)f2bf(hi.z); v[7] = (short)f2bf(hi.w);
  return v;
}

// One-shot f32 -> bf16 preconversion of both feature tensors.
__global__ __launch_bounds__(256) void conv_kernel(
    const float* __restrict__ v, const float* __restrict__ w,
    unsigned short* __restrict__ vb, unsigned short* __restrict__ wb) {
  const int idx = blockIdx.x * 256 + threadIdx.x;   // float4 units
  float4 a = reinterpret_cast<const float4*>(v)[idx];
  float4 b = reinterpret_cast<const float4*>(w)[idx];
  u16x4 pa, pb;
  pa[0] = f2bf(a.x); pa[1] = f2bf(a.y); pa[2] = f2bf(a.z); pa[3] = f2bf(a.w);
  pb[0] = f2bf(b.x); pb[1] = f2bf(b.y); pb[2] = f2bf(b.z); pb[3] = f2bf(b.w);
  reinterpret_cast<u16x4*>(vb)[idx] = pa;
  reinterpret_cast<u16x4*>(wb)[idx] = pb;
}

// One workgroup per (i,j).  Dual-orientation GEMM with 32x32x16 MFMA:
//   waves 0-3: S  = video x wifi^T   (chunked 64 rows x 64 cols each)
//   waves 4-7: St = wifi  x video^T
// Both poolings then reduce over the REGISTER-LOCAL row axis of the 32x32
// C/D layout (col=lane&31, row=(reg&3)+8*(reg>>2)+4*(lane>>5)): 31 local
// fmax + one shfl_xor(32) + a 2-entry LDS partial combine.
// LDS: 2 x 32KiB double-buffered bf16 panels (A,B) + 8 KiB partials.
template <bool PRE>
__global__ __launch_bounds__(512, 4) void pair_kernel(
    const float* __restrict__ videof, const float* __restrict__ wifif,
    const unsigned short* __restrict__ videob,
    const unsigned short* __restrict__ wifib,
    float* __restrict__ dense) {
  __shared__ __align__(16) char lds[73728];
  const int tid = threadIdx.x;
  const int bid = blockIdx.x;
  const int bi = bid >> 6, bj = bid & 63;
  const int wid = tid >> 6, l = tid & 63;
  const int l31 = l & 31;

  // wave roles
  const int o  = wid >> 2;          // 0: S, 1: St
  const int mg = wid & 1;           // 64-row group of X
  const int cg = (wid >> 1) & 1;    // 64-col group of Y

  // ---- staging constants ----
  const char* vsrc = (const char*)videob + (size_t)bi * (TT * DD * 2);
  const char* wsrc = (const char*)wifib  + (size_t)bj * (TT * DD * 2);
  // PRE path (global_load_lds): chunk q (0..31) -> 1 KiB; lane writes 16B at
  // linear slot; source address inverse-swizzled so that swizzled READS work.
  const int grow8 = l >> 3;                       // row within 8-row chunk
  const int gcb   = ((l & 7) ^ grow8) << 4;       // inverse-swizzled src byte
  // non-PRE path (reg staging, as R4)
  const int srow = tid >> 2;
  const int scb  = (tid & 3) * 32;
  const int sswz = (srow & 7) << 4;
  const int sb0  = srow * 128 + ((scb) ^ sswz);
  const int sb1  = srow * 128 + ((scb + 16) ^ sswz);

  f32x16 acc[2][2];
#pragma unroll
  for (int mi = 0; mi < 2; ++mi)
#pragma unroll
    for (int t = 0; t < 2; ++t)
#pragma unroll
      for (int r = 0; r < 16; ++r) acc[mi][t][r] = 0.f;

  // frag addresses: X panel = own rows, Y panel = other matrix
  const int apan = o ? 16384 : 0;
  const int bpan = o ? 0 : 16384;
  const int xr   = (l & 7) << 4;                  // read-side swizzle
  const int khalf = (l >> 5) * 16;                // byte k-chunk within 32B step
  const int x0 = (mg * 64 + l31) * 128;
  const int x1 = (mg * 64 + 32 + l31) * 128;
  const int y0 = (cg * 64 + l31) * 128;
  const int y1 = (cg * 64 + 32 + l31) * 128;

#define STAGE_PRE(KP, BUF)                                                    \
  do {                                                                        \
    _Pragma("unroll") for (int k_ = 0; k_ < 4; ++k_) {                        \
      const int q_ = wid * 4 + k_;                                            \
      const int c_ = q_ & 15;                                                 \
      const char* s_ = ((q_ < 16) ? vsrc : wsrc) + (c_ * 8 + grow8) * 512 +   \
                       (KP) * 128 + gcb;                                      \
      char* d_ = lds + (BUF) * 32768 + ((q_ < 16) ? 0 : 16384) + c_ * 1024;   \
      __builtin_amdgcn_global_load_lds((const void*)s_, (void*)d_, 16, 0, 0); \
    }                                                                         \
  } while (0)

#define STAGE_REG(KP, BUF)                                                    \
  do {                                                                        \
    const float* pa_ = videof + (size_t)bi * (TT * DD) + srow * DD +          \
                       (KP) * BK + (tid & 3) * 16;                            \
    const float* pb_ = wifif + (size_t)bj * (TT * DD) + srow * DD +           \
                       (KP) * BK + (tid & 3) * 16;                            \
    float4 a0_ = *(const float4*)(pa_);                                       \
    float4 a1_ = *(const float4*)(pa_ + 4);                                   \
    float4 a2_ = *(const float4*)(pa_ + 8);                                   \
    float4 a3_ = *(const float4*)(pa_ + 12);                                  \
    float4 b0_ = *(const float4*)(pb_);                                       \
    float4 b1_ = *(const float4*)(pb_ + 4);                                   \
    float4 b2_ = *(const float4*)(pb_ + 8);                                   \
    float4 b3_ = *(const float4*)(pb_ + 12);                                  \
    char* base_ = lds + (BUF) * 32768;                                        \
    *(bf16x8*)(base_ + sb0)         = pack8(a0_, a1_);                        \
    *(bf16x8*)(base_ + sb1)         = pack8(a2_, a3_);                        \
    *(bf16x8*)(base_ + 16384 + sb0) = pack8(b0_, b1_);                        \
    *(bf16x8*)(base_ + 16384 + sb1) = pack8(b2_, b3_);                        \
  } while (0)

  // prologue: stage panel 0 into buf 0
  if constexpr (PRE) STAGE_PRE(0, 0); else STAGE_REG(0, 0);
  __syncthreads();

  for (int kp = 0; kp < 4; ++kp) {
    const int bufoff = (kp & 1) * 32768;
    if (kp < 3) {                       // prefetch next panel into other buf
      if constexpr (PRE) STAGE_PRE(kp + 1, (kp + 1) & 1);
      else STAGE_REG(kp + 1, (kp + 1) & 1);
    }
#pragma unroll
    for (int ks = 0; ks < 4; ++ks) {
      const int cb = ks * 32 + khalf;
      bf16x8 ax0 = *(const bf16x8*)(lds + bufoff + apan + x0 + (cb ^ xr));
      bf16x8 ax1 = *(const bf16x8*)(lds + bufoff + apan + x1 + (cb ^ xr));
      bf16x8 by0 = *(const bf16x8*)(lds + bufoff + bpan + y0 + (cb ^ xr));
      bf16x8 by1 = *(const bf16x8*)(lds + bufoff + bpan + y1 + (cb ^ xr));
      acc[0][0] = __builtin_amdgcn_mfma_f32_32x32x16_bf16(ax0, by0, acc[0][0], 0, 0, 0);
      acc[0][1] = __builtin_amdgcn_mfma_f32_32x32x16_bf16(ax0, by1, acc[0][1], 0, 0, 0);
      acc[1][0] = __builtin_amdgcn_mfma_f32_32x32x16_bf16(ax1, by0, acc[1][0], 0, 0, 0);
      acc[1][1] = __builtin_amdgcn_mfma_f32_32x32x16_bf16(ax1, by1, acc[1][1], 0, 0, 0);
    }
    __syncthreads();                    // next panel staged + this one consumed
  }

  // ---- pooling partials:  [o][mg][128] f32 each ----
  float* PM = (float*)(lds + 65536);    // max
  float* PS = PM + 512;                 // sum exp
  float* PV = PM + 1024;                // sum exp*v
  float* Gb = PM + 1536;                // 2 scalars
  const int colb = cg * 64;

  // pass A: per-column max over this wave's 64 rows (reg-local + shfl32)
#pragma unroll
  for (int t = 0; t < 2; ++t) {
    float mx = acc[0][t][0];
#pragma unroll
    for (int mi = 0; mi < 2; ++mi)
#pragma unroll
      for (int r = 0; r < 16; ++r) mx = fmaxf(mx, acc[mi][t][r]);
    mx = fmaxf(mx, __shfl_xor(mx, 32));
    if (l < 32) PM[o * 256 + mg * 128 + colb + t * 32 + l] = mx;
  }
  __syncthreads();

  // pass B: exp-sums with the global (128-row) max
#pragma unroll
  for (int t = 0; t < 2; ++t) {
    const int c = colb + t * 32 + l31;
    const float mx = fmaxf(PM[o * 256 + c], PM[o * 256 + 128 + c]);
    float se = 0.f, sv = 0.f;
#pragma unroll
    for (int mi = 0; mi < 2; ++mi)
#pragma unroll
      for (int r = 0; r < 16; ++r) {
        const float v = acc[mi][t][r];
        const float e = __expf((v - mx) * 2.0f);   // /tau = *2
        se += e;
        sv = fmaf(e, v, sv);
      }
    se += __shfl_xor(se, 32);
    sv += __shfl_xor(sv, 32);
    if (l < 32) {
      PS[o * 256 + mg * 128 + c] = se;
      PV[o * 256 + mg * 128 + c] = sv;
    }
  }
  __syncthreads();

  // pass C: frame-level softmax pooling -> scalars
  // wave 0: sv (video rows, from o=1 partials); wave 1: sw (wifi cols, o=0)
  if (wid < 2) {
    const int oo = wid == 0 ? 1 : 0;
    const float* PSo = PS + oo * 256;
    const float* PVo = PV + oo * 256;
    float a0 = (PVo[l] + PVo[128 + l]) / (PSo[l] + PSo[128 + l]);
    float a1 = (PVo[64 + l] + PVo[192 + l]) / (PSo[64 + l] + PSo[192 + l]);
    float mx = fmaxf(a0, a1);
#pragma unroll
    for (int s = 1; s < 64; s <<= 1) mx = fmaxf(mx, __shfl_xor(mx, s));
    float e0 = __expf((a0 - mx) * 2.0f), e1 = __expf((a1 - mx) * 2.0f);
    float se = e0 + e1, sev = e0 * a0 + e1 * a1;
#pragma unroll
    for (int s = 1; s < 64; s <<= 1) { se += __shfl_xor(se, s); sev += __shfl_xor(sev, s); }
    if (l == 0) Gb[wid] = sev / se;
  }
  __syncthreads();
  if (tid == 0) dense[bid] = 0.5f * (Gb[0] + Gb[1]);
}

// Label-smoothed symmetric CE over the 64x64 dense-similarity matrix. f32 out.
__global__ __launch_bounds__(64) void loss_kernel(
    const float* __restrict__ dense, const float* __restrict__ scalep,
    float* __restrict__ out) {
  const int i = threadIdx.x;
  const float sc = fminf(scalep[0], 40.0f);
  float mxr = -3.4e38f, mxc = -3.4e38f;
  for (int j = 0; j < 64; ++j) {
    mxr = fmaxf(mxr, sc * dense[i * 64 + j]);
    mxc = fmaxf(mxc, sc * dense[j * 64 + i]);
  }
  float ser = 0.f, sec = 0.f, slr = 0.f, slc = 0.f;
  for (int j = 0; j < 64; ++j) {
    float zr = sc * dense[i * 64 + j];
    float zc = sc * dense[j * 64 + i];
    ser += __expf(zr - mxr); sec += __expf(zc - mxc);
    slr += zr;               slc += zc;
  }
  const float lser = mxr + logf(ser);
  const float lsec = mxc + logf(sec);
  const float zd = sc * dense[i * 65];
  float lv = lser - 0.9f * zd - 0.1f * (slr * (1.0f / 64.0f));
  float lw = lsec - 0.9f * zd - 0.1f * (slc * (1.0f / 64.0f));
  float t = 0.5f * (lv + lw);
#pragma unroll
  for (int s = 1; s < 64; s <<= 1) t += __shfl_xor(t, s);
  if (i == 0) out[0] = t * (1.0f / 64.0f);
}

extern "C" void kernel_launch(void* const* d_in, const int* in_sizes, int n_in,
                              void* d_out, int out_size, void* d_ws, size_t ws_size,
                              hipStream_t stream) {
  (void)in_sizes; (void)n_in; (void)out_size;
  const float* video = (const float*)d_in[0];
  const float* wifi  = (const float*)d_in[1];
  const float* scale = (const float*)d_in[2];
  float* dense = (float*)d_ws;                                   // 16 KiB
  unsigned short* vb = (unsigned short*)((char*)d_ws + 16384);   // 4 MiB
  unsigned short* wb = vb + 64 * TT * DD;                        // 4 MiB

  const bool pre = ws_size >= (size_t)16384 + 2u * 64 * TT * DD * 2;
  if (pre) {
    hipLaunchKernelGGL(conv_kernel, dim3(2048), dim3(256), 0, stream,
                       video, wifi, vb, wb);
    hipLaunchKernelGGL((pair_kernel<true>), dim3(64 * 64), dim3(512), 0, stream,
                       video, wifi, vb, wb, dense);
  } else {
    hipLaunchKernelGGL((pair_kernel<false>), dim3(64 * 64), dim3(512), 0, stream,
                       video, wifi, vb, wb, dense);
  }
  hipLaunchKernelGGL(loss_kernel, dim3(1), dim3(64), 0, stream,
                     dense, scale, (float*)d_out);
}

// Round 6
// 97.414 us; speedup vs baseline: 1.0442x; 1.0442x over previous
//
#include <hip/hip_runtime.h>
#include <hip/hip_bf16.h>

typedef __attribute__((ext_vector_type(8))) short bf16x8;
typedef __attribute__((ext_vector_type(16))) float f32x16;
typedef __attribute__((ext_vector_type(4))) unsigned short u16x4;

#define TT 128
#define DD 256
#define BK 64

__device__ __forceinline__ unsigned short f2bf(float f) {
  unsigned int x = __float_as_uint(f);
  x += 0x7fffu + ((x >> 16) & 1u);          // round-to-nearest-even
  return (unsigned short)(x >> 16);
}

__device__ __forceinline__ bf16x8 pack8(float4 lo, float4 hi) {
  bf16x8 v;
  v[0] = (short)f2bf(lo.x); v[1] = (short)f2bf(lo.y);
  v[2] = (short)f2bf(lo.z); v[3] = (short)f2bf(lo.w);
  v[4] = (short)f2bf(hi.x); v[5] = (short)f2bf(hi.y);
  v[6] = (short)f2bf(hi.z); v[7] = (short)f2bf(hi.w);
  return v;
}

// One-shot f32 -> bf16 preconversion of both feature tensors.
__global__ __launch_bounds__(256) void conv_kernel(
    const float* __restrict__ v, const float* __restrict__ w,
    unsigned short* __restrict__ vb, unsigned short* __restrict__ wb) {
  const int idx = blockIdx.x * 256 + threadIdx.x;   // float4 units
  float4 a = reinterpret_cast<const float4*>(v)[idx];
  float4 b = reinterpret_cast<const float4*>(w)[idx];
  u16x4 pa, pb;
  pa[0] = f2bf(a.x); pa[1] = f2bf(a.y); pa[2] = f2bf(a.z); pa[3] = f2bf(a.w);
  pb[0] = f2bf(b.x); pb[1] = f2bf(b.y); pb[2] = f2bf(b.z); pb[3] = f2bf(b.w);
  reinterpret_cast<u16x4*>(vb)[idx] = pa;
  reinterpret_cast<u16x4*>(wb)[idx] = pb;
}

// One workgroup (256 thr, 4 waves) per (i,j).  Dual-orientation GEMM,
// 32x32x16 MFMA, FAT wave tiles 64 rows x 128 cols (8 MFMA per 6 ds_reads):
//   wave 0/1: S  = video x wifi^T, row-halves 0/1
//   wave 2/3: St = wifi  x video^T, row-halves 0/1
// Pooling reduces over the register-local row axis of the 32x32 C/D layout
// (col=lane&31, row=(reg&3)+8*(reg>>2)+4*(lane>>5)) + one shfl_xor(32) +
// a 2-entry LDS combine.  LDS: 2x32KiB double-buffered panels + partials.
template <bool PRE>
__global__ __launch_bounds__(256, 2) void pair_kernel(
    const float* __restrict__ videof, const float* __restrict__ wifif,
    const unsigned short* __restrict__ videob,
    const unsigned short* __restrict__ wifib,
    float* __restrict__ dense) {
  __shared__ __align__(16) char lds[73728];
  const int tid = threadIdx.x;
  const int bid = blockIdx.x;
  const int bi = bid >> 6, bj = bid & 63;
  const int wid = tid >> 6, l = tid & 63;
  const int l31 = l & 31;

  const int o  = wid >> 1;          // 0: S, 1: St
  const int mg = wid & 1;           // 64-row half of X

  // ---- staging constants ----
  const char* vsrc = (const char*)videob + (size_t)bi * (TT * DD * 2);
  const char* wsrc = (const char*)wifib  + (size_t)bj * (TT * DD * 2);
  // PRE: chunk q (0..31) = 8 rows x 128B, linear LDS dest; source address
  // inverse-swizzled so that ^((row&7)<<4) READS come back correct.
  const int grow8 = l >> 3;
  const int gcb   = ((l & 7) ^ grow8) << 4;
  // non-PRE fallback: thread handles 64B halves of row srow for A and B
  const int srow = tid >> 1;
  const int scb  = (tid & 1) * 64;
  const int sswz = (srow & 7) << 4;

  f32x16 acc[2][4];
#pragma unroll
  for (int mi = 0; mi < 2; ++mi)
#pragma unroll
    for (int t = 0; t < 4; ++t)
#pragma unroll
      for (int r = 0; r < 16; ++r) acc[mi][t][r] = 0.f;

  const int apan = o ? 16384 : 0;   // X panel (own rows)
  const int bpan = o ? 0 : 16384;   // Y panel (other matrix)
  const int xr    = (l & 7) << 4;   // read-side swizzle
  const int khalf = (l >> 5) * 16;
  const int x0 = (mg * 64 + l31) * 128;     // +4096 for second 32-row tile
  const int y0 = l31 * 128;                 // +t*4096 for col 32-tiles

#define STAGE_PRE(KP, BUF)                                                    \
  do {                                                                        \
    _Pragma("unroll") for (int k_ = 0; k_ < 8; ++k_) {                        \
      const int q_ = wid * 8 + k_;                                            \
      const int c_ = q_ & 15;                                                 \
      const char* s_ = ((q_ < 16) ? vsrc : wsrc) + (c_ * 8 + grow8) * 512 +   \
                       (KP) * 128 + gcb;                                      \
      char* d_ = lds + (BUF) * 32768 + ((q_ < 16) ? 0 : 16384) + c_ * 1024;   \
      __builtin_amdgcn_global_load_lds((const void*)s_, (void*)d_, 16, 0, 0); \
    }                                                                         \
  } while (0)

#define STAGE_REG(KP, BUF)                                                    \
  do {                                                                        \
    const float* pa_ = videof + (size_t)bi * (TT * DD) + srow * DD +          \
                       (KP) * BK + (tid & 1) * 32;                            \
    const float* pb_ = wifif + (size_t)bj * (TT * DD) + srow * DD +           \
                       (KP) * BK + (tid & 1) * 32;                            \
    char* base_ = lds + (BUF) * 32768;                                        \
    _Pragma("unroll") for (int h_ = 0; h_ < 2; ++h_) {                        \
      float4 a0_ = *(const float4*)(pa_ + h_ * 16);                           \
      float4 a1_ = *(const float4*)(pa_ + h_ * 16 + 4);                       \
      float4 a2_ = *(const float4*)(pa_ + h_ * 16 + 8);                       \
      float4 a3_ = *(const float4*)(pa_ + h_ * 16 + 12);                      \
      float4 b0_ = *(const float4*)(pb_ + h_ * 16);                           \
      float4 b1_ = *(const float4*)(pb_ + h_ * 16 + 4);                       \
      float4 b2_ = *(const float4*)(pb_ + h_ * 16 + 8);                       \
      float4 b3_ = *(const float4*)(pb_ + h_ * 16 + 12);                      \
      const int c0_ = srow * 128 + ((scb + h_ * 32) ^ sswz);                  \
      const int c1_ = srow * 128 + ((scb + h_ * 32 + 16) ^ sswz);             \
      *(bf16x8*)(base_ + c0_)         = pack8(a0_, a1_);                      \
      *(bf16x8*)(base_ + c1_)         = pack8(a2_, a3_);                      \
      *(bf16x8*)(base_ + 16384 + c0_) = pack8(b0_, b1_);                      \
      *(bf16x8*)(base_ + 16384 + c1_) = pack8(b2_, b3_);                      \
    }                                                                         \
  } while (0)

  if constexpr (PRE) STAGE_PRE(0, 0); else STAGE_REG(0, 0);
  __syncthreads();

  for (int kp = 0; kp < 4; ++kp) {
    const int bufoff = (kp & 1) * 32768;
    if (kp < 3) {                       // prefetch next panel into other buf
      if constexpr (PRE) STAGE_PRE(kp + 1, (kp + 1) & 1);
      else STAGE_REG(kp + 1, (kp + 1) & 1);
    }
#pragma unroll
    for (int ks = 0; ks < 4; ++ks) {
      const int cb = ks * 32 + khalf;
      const char* xb = lds + bufoff + apan;
      const char* yb = lds + bufoff + bpan;
      bf16x8 ax0 = *(const bf16x8*)(xb + x0 + (cb ^ xr));
      bf16x8 ax1 = *(const bf16x8*)(xb + x0 + 4096 + (cb ^ xr));
      bf16x8 by0 = *(const bf16x8*)(yb + y0 + (cb ^ xr));
      bf16x8 by1 = *(const bf16x8*)(yb + y0 + 4096 + (cb ^ xr));
      bf16x8 by2 = *(const bf16x8*)(yb + y0 + 8192 + (cb ^ xr));
      bf16x8 by3 = *(const bf16x8*)(yb + y0 + 12288 + (cb ^ xr));
      acc[0][0] = __builtin_amdgcn_mfma_f32_32x32x16_bf16(ax0, by0, acc[0][0], 0, 0, 0);
      acc[0][1] = __builtin_amdgcn_mfma_f32_32x32x16_bf16(ax0, by1, acc[0][1], 0, 0, 0);
      acc[0][2] = __builtin_amdgcn_mfma_f32_32x32x16_bf16(ax0, by2, acc[0][2], 0, 0, 0);
      acc[0][3] = __builtin_amdgcn_mfma_f32_32x32x16_bf16(ax0, by3, acc[0][3], 0, 0, 0);
      acc[1][0] = __builtin_amdgcn_mfma_f32_32x32x16_bf16(ax1, by0, acc[1][0], 0, 0, 0);
      acc[1][1] = __builtin_amdgcn_mfma_f32_32x32x16_bf16(ax1, by1, acc[1][1], 0, 0, 0);
      acc[1][2] = __builtin_amdgcn_mfma_f32_32x32x16_bf16(ax1, by2, acc[1][2], 0, 0, 0);
      acc[1][3] = __builtin_amdgcn_mfma_f32_32x32x16_bf16(ax1, by3, acc[1][3], 0, 0, 0);
    }
    __syncthreads();                    // panel consumed + next staged
  }

  // ---- pooling partials: [o][mg][128] f32 each ----
  float* PM = (float*)(lds + 65536);    // max
  float* PS = PM + 512;                 // sum exp
  float* PV = PM + 1024;                // sum exp*v
  float* Gb = PM + 1536;                // 2 scalars

  // pass A: per-col max over this wave's 64 rows (reg-local + shfl32)
#pragma unroll
  for (int t = 0; t < 4; ++t) {
    float mx = acc[0][t][0];
#pragma unroll
    for (int mi = 0; mi < 2; ++mi)
#pragma unroll
      for (int r = 0; r < 16; ++r) mx = fmaxf(mx, acc[mi][t][r]);
    mx = fmaxf(mx, __shfl_xor(mx, 32));
    if (l < 32) PM[o * 256 + mg * 128 + t * 32 + l] = mx;
  }
  __syncthreads();

  // pass B: exp-sums with the global (128-row) max
#pragma unroll
  for (int t = 0; t < 4; ++t) {
    const int c = t * 32 + l31;
    const float mx = fmaxf(PM[o * 256 + c], PM[o * 256 + 128 + c]);
    float se = 0.f, sv = 0.f;
#pragma unroll
    for (int mi = 0; mi < 2; ++mi)
#pragma unroll
      for (int r = 0; r < 16; ++r) {
        const float v = acc[mi][t][r];
        const float e = __expf((v - mx) * 2.0f);   // /tau = *2
        se += e;
        sv = fmaf(e, v, sv);
      }
    se += __shfl_xor(se, 32);
    sv += __shfl_xor(sv, 32);
    if (l < 32) {
      PS[o * 256 + mg * 128 + c] = se;
      PV[o * 256 + mg * 128 + c] = sv;
    }
  }
  __syncthreads();

  // pass C: frame-level softmax pooling -> scalars
  // wave 0: v2w (video frames, o=1 partials); wave 1: w2v (wifi, o=0)
  if (wid < 2) {
    const int oo = wid == 0 ? 1 : 0;
    const float* PSo = PS + oo * 256;
    const float* PVo = PV + oo * 256;
    float a0 = (PVo[l] + PVo[128 + l]) / (PSo[l] + PSo[128 + l]);
    float a1 = (PVo[64 + l] + PVo[192 + l]) / (PSo[64 + l] + PSo[192 + l]);
    float mx = fmaxf(a0, a1);
#pragma unroll
    for (int s = 1; s < 64; s <<= 1) mx = fmaxf(mx, __shfl_xor(mx, s));
    float e0 = __expf((a0 - mx) * 2.0f), e1 = __expf((a1 - mx) * 2.0f);
    float se = e0 + e1, sev = e0 * a0 + e1 * a1;
#pragma unroll
    for (int s = 1; s < 64; s <<= 1) { se += __shfl_xor(se, s); sev += __shfl_xor(sev, s); }
    if (l == 0) Gb[wid] = sev / se;
  }
  __syncthreads();
  if (tid == 0) dense[bid] = 0.5f * (Gb[0] + Gb[1]);
}

// Label-smoothed symmetric CE over the 64x64 dense-similarity matrix. f32 out.
__global__ __launch_bounds__(64) void loss_kernel(
    const float* __restrict__ dense, const float* __restrict__ scalep,
    float* __restrict__ out) {
  const int i = threadIdx.x;
  const float sc = fminf(scalep[0], 40.0f);
  float mxr = -3.4e38f, mxc = -3.4e38f;
  for (int j = 0; j < 64; ++j) {
    mxr = fmaxf(mxr, sc * dense[i * 64 + j]);
    mxc = fmaxf(mxc, sc * dense[j * 64 + i]);
  }
  float ser = 0.f, sec = 0.f, slr = 0.f, slc = 0.f;
  for (int j = 0; j < 64; ++j) {
    float zr = sc * dense[i * 64 + j];
    float zc = sc * dense[j * 64 + i];
    ser += __expf(zr - mxr); sec += __expf(zc - mxc);
    slr += zr;               slc += zc;
  }
  const float lser = mxr + logf(ser);
  const float lsec = mxc + logf(sec);
  const float zd = sc * dense[i * 65];
  float lv = lser - 0.9f * zd - 0.1f * (slr * (1.0f / 64.0f));
  float lw = lsec - 0.9f * zd - 0.1f * (slc * (1.0f / 64.0f));
  float t = 0.5f * (lv + lw);
#pragma unroll
  for (int s = 1; s < 64; s <<= 1) t += __shfl_xor(t, s);
  if (i == 0) out[0] = t * (1.0f / 64.0f);
}

extern "C" void kernel_launch(void* const* d_in, const int* in_sizes, int n_in,
                              void* d_out, int out_size, void* d_ws, size_t ws_size,
                              hipStream_t stream) {
  (void)in_sizes; (void)n_in; (void)out_size;
  const float* video = (const float*)d_in[0];
  const float* wifi  = (const float*)d_in[1];
  const float* scale = (const float*)d_in[2];
  float* dense = (float*)d_ws;                                   // 16 KiB
  unsigned short* vb = (unsigned short*)((char*)d_ws + 16384);   // 4 MiB
  unsigned short* wb = vb + 64 * TT * DD;                        // 4 MiB

  const bool pre = ws_size >= (size_t)16384 + 2u * 64 * TT * DD * 2;
  if (pre) {
    hipLaunchKernelGGL(conv_kernel, dim3(2048), dim3(256), 0, stream,
                       video, wifi, vb, wb);
    hipLaunchKernelGGL((pair_kernel<true>), dim3(64 * 64), dim3(256), 0, stream,
                       video, wifi, vb, wb, dense);
  } else {
    hipLaunchKernelGGL((pair_kernel<false>), dim3(64 * 64), dim3(256), 0, stream,
                       video, wifi, vb, wb, dense);
  }
  hipLaunchKernelGGL(loss_kernel, dim3(1), dim3(64), 0, stream,
                     dense, scale, (float*)d_out);
}